// Round 8
// baseline (115.115 us; speedup 1.0000x reference)
//
#include <hip/hip_runtime.h>
#include <hip/hip_bf16.h>
#include <math.h>

#define TPB 64

typedef float f32x4 __attribute__((ext_vector_type(4)));

// Wave-local LDS fence: workgroup == 1 wave, so cross-lane LDS visibility only
// needs lgkmcnt(0); sched_barrier(0) keeps the compiler from hoisting LDS ops past it.
__device__ __forceinline__ void wave_lds_fence() {
    __builtin_amdgcn_sched_barrier(0);
    asm volatile("s_waitcnt lgkmcnt(0)" ::: "memory");
    __builtin_amdgcn_sched_barrier(0);
}

// D = Za @ J @ Zb @ J @ Zc  (reference z-rot structure: Z[i][i]=cs[i], Z[i][DIM-1-i]=sn[i])
template<int DIM>
__device__ __forceinline__ void zchain(
    const float* __restrict__ J,
    const float (&ca)[DIM], const float (&sa)[DIM],
    const float (&cb)[DIM], const float (&sb)[DIM],
    const float (&cc)[DIM], const float (&sc)[DIM],
    float (&D)[DIM][DIM])
{
    constexpr int d1 = DIM - 1;
    float Jl[DIM][DIM];
#pragma unroll
    for (int i = 0; i < DIM; ++i)
#pragma unroll
        for (int j = 0; j < DIM; ++j)
            Jl[i][j] = J[i * DIM + j];   // uniform -> scalar loads

    float U[DIM][DIM];
#pragma unroll
    for (int i = 0; i < DIM; ++i)
#pragma unroll
        for (int j = 0; j < DIM; ++j)
            U[i][j] = ca[i] * Jl[i][j] + sa[i] * Jl[d1 - i][j];     // Za @ J

    float V[DIM][DIM];
#pragma unroll
    for (int i = 0; i < DIM; ++i)
#pragma unroll
        for (int j = 0; j < DIM; ++j)
            V[i][j] = U[i][j] * cb[j] + U[i][d1 - j] * sb[d1 - j];  // (.) @ Zb

    float W[DIM][DIM];
#pragma unroll
    for (int i = 0; i < DIM; ++i)
#pragma unroll
        for (int j = 0; j < DIM; ++j) {
            float acc = 0.f;
#pragma unroll
            for (int k = 0; k < DIM; ++k)
                acc = fmaf(V[i][k], Jl[k][j], acc);                 // (.) @ J
            W[i][j] = acc;
        }
#pragma unroll
    for (int i = 0; i < DIM; ++i)
#pragma unroll
        for (int j = 0; j < DIM; ++j)
            D[i][j] = W[i][j] * cc[j] + W[i][d1 - j] * sc[d1 - j];  // (.) @ Zc
}

// to_m permutation (reference _build_to_m): order = [0,2,6,3,7,1,5,8,4]
// => wm rows (m=0..8) come from: e0, D1r1, D2r2, D1r2, D2r3, D1r0, D2r1, D2r4, D2r0; wm_inv = wm^T.

__global__ __launch_bounds__(TPB) void wigner_kernel(
    const float* __restrict__ vec, const float* __restrict__ rnd,
    const float* __restrict__ J1,  const float* __restrict__ J2,
    float* __restrict__ outR,
    float* __restrict__ outWm,
    float* __restrict__ outWi,
    int E)
{
    __shared__ __align__(16) float ldsR[TPB * 9];
    __shared__ __align__(16) float ldsW[TPB * 81];

    const int t  = threadIdx.x;
    const int e0 = blockIdx.x * TPB;
    const int e  = e0 + t;
    const int ei = (e < E) ? e : (E - 1);
    const int nvalid = min(TPB, E - e0);

    // ---------------- per-edge math (f32, no transcendentals) ----------------
    float vx = vec[3 * ei + 0], vy = vec[3 * ei + 1], vz = vec[3 * ei + 2];
    float rn = rsqrtf(vx * vx + vy * vy + vz * vz);
    float nx0 = vx * rn, nx1 = vy * rn, nx2 = vz * rn;     // norm_x

    float ox = rnd[3 * ei + 0] - 0.5f;
    float oy = rnd[3 * ei + 1] - 0.5f;
    float oz = rnd[3 * ei + 2] - 0.5f;
    float ro = rsqrtf(ox * ox + oy * oy + oz * oz);
    ox *= ro; oy *= ro; oz *= ro;                          // original e2

    // candidate selection (e2b, e2c from ORIGINAL e2)
    float sx = ox, sy = oy, sz = oz;
    float dcur = fabsf(sx * nx0 + sy * nx1 + sz * nx2);
    {
        float bx = -oy, by = ox, bz = oz;
        float db = fabsf(bx * nx0 + by * nx1 + bz * nx2);
        if (dcur > db) { sx = bx; sy = by; sz = bz; dcur = db; }
        float cx = ox, cy = -oz, cz = oy;
        float dc = fabsf(cx * nx0 + cy * nx1 + cz * nx2);
        if (dcur > dc) { sx = cx; sy = cy; sz = cz; }
    }

    // norm_z = normalize(cross(norm_x, e2))
    float zx = nx1 * sz - nx2 * sy;
    float zy = nx2 * sx - nx0 * sz;
    float zz = nx0 * sy - nx1 * sx;
    float rz = rsqrtf(zx * zx + zy * zy + zz * zz);
    zx *= rz; zy *= rz; zz *= rz;

    // norm_y = normalize(cross(norm_x, norm_z))
    float yx = nx1 * zz - nx2 * zy;
    float yy = nx2 * zx - nx0 * zz;
    float yz = nx0 * zy - nx1 * zx;
    float ry = rsqrtf(yx * yx + yy * yy + yz * yz);
    yx *= ry; yy *= ry; yz *= ry;

    // ---- sin/cos of Euler angles, algebraically (no atan2/acos/sincos) ----
    float h2a = zy * zy + yy * yy;
    float rha = rsqrtf(fmaxf(h2a, 1e-30f));
    bool  za  = (h2a < 1e-24f);
    float sa  = za ? 0.f : zy * rha;
    float caa = za ? 1.f : yy * rha;
    float cbb = fminf(1.f, fmaxf(-1.f, nx1));
    float sb  = sqrtf(fmaxf(0.f, 1.f - cbb * cbb));
    float gy  = caa * zz - sa * yz;
    float gx  = caa * zx - sa * yx;
    float h2g = gy * gy + gx * gx;
    float rhg = rsqrtf(fmaxf(h2g, 1e-30f));
    bool  zg  = (h2g < 1e-24f);
    float sg  = zg ? 0.f : gy * rhg;
    float cgg = zg ? 1.f : gx * rhg;

    // l = 1 block
    float ca3[3] = {caa, 1.f, caa}, sa3[3] = {sa, 0.f, -sa};
    float cb3[3] = {cbb, 1.f, cbb}, sb3[3] = {sb, 0.f, -sb};
    float cc3[3] = {cgg, 1.f, cgg}, sc3[3] = {sg, 0.f, -sg};
    float D1[3][3];
    zchain<3>(J1, ca3, sa3, cb3, sb3, cc3, sc3, D1);

    // l = 2 block (double angles via identities)
    float ca2 = caa * caa - sa * sa,  sa2 = 2.f * sa * caa;
    float cb2 = cbb * cbb - sb * sb,  sb2 = 2.f * sb * cbb;
    float cg2 = cgg * cgg - sg * sg,  sg2 = 2.f * sg * cgg;
    float ca5[5] = {ca2, caa, 1.f, caa, ca2}, sa5[5] = {sa2, sa, 0.f, -sa, -sa2};
    float cb5[5] = {cb2, cbb, 1.f, cbb, cb2}, sb5[5] = {sb2, sb, 0.f, -sb, -sb2};
    float cc5[5] = {cg2, cgg, 1.f, cgg, cg2}, sc5[5] = {sg2, sg, 0.f, -sg, -sg2};
    float D2[5][5];
    zchain<5>(J2, ca5, sa5, cb5, sb5, cc5, sc5, D2);

    // ---------------- build R and wm (static layout) ----------------
    {
        float* r9 = &ldsR[t * 9];
        r9[0] = zx;  r9[1] = zy;  r9[2] = zz;
        r9[3] = nx0; r9[4] = nx1; r9[5] = nx2;
        r9[6] = yx;  r9[7] = yy;  r9[8] = yz;

        float* w = &ldsW[t * 81];
        w[0] = 1.f;
#pragma unroll
        for (int c = 1; c < 9; ++c) w[c] = 0.f;
        w[9]  = 0.f; w[10] = D1[1][0]; w[11] = D1[1][1]; w[12] = D1[1][2];
#pragma unroll
        for (int c = 4; c < 9; ++c) w[9 + c] = 0.f;
#pragma unroll
        for (int c = 0; c < 4; ++c) w[18 + c] = 0.f;
#pragma unroll
        for (int c = 0; c < 5; ++c) w[22 + c] = D2[2][c];
        w[27] = 0.f; w[28] = D1[2][0]; w[29] = D1[2][1]; w[30] = D1[2][2];
#pragma unroll
        for (int c = 4; c < 9; ++c) w[27 + c] = 0.f;
#pragma unroll
        for (int c = 0; c < 4; ++c) w[36 + c] = 0.f;
#pragma unroll
        for (int c = 0; c < 5; ++c) w[40 + c] = D2[3][c];
        w[45] = 0.f; w[46] = D1[0][0]; w[47] = D1[0][1]; w[48] = D1[0][2];
#pragma unroll
        for (int c = 4; c < 9; ++c) w[45 + c] = 0.f;
#pragma unroll
        for (int c = 0; c < 4; ++c) w[54 + c] = 0.f;
#pragma unroll
        for (int c = 0; c < 5; ++c) w[58 + c] = D2[1][c];
#pragma unroll
        for (int c = 0; c < 4; ++c) w[63 + c] = 0.f;
#pragma unroll
        for (int c = 0; c < 5; ++c) w[67 + c] = D2[4][c];
#pragma unroll
        for (int c = 0; c < 4; ++c) w[72 + c] = 0.f;
#pragma unroll
        for (int c = 0; c < 5; ++c) w[76 + c] = D2[0][c];
    }
    wave_lds_fence();

    // ---------------- copy-out R and wm (coalesced f32x4, PLAIN stores — NT A/B) ----------------
    if (nvalid == TPB) {
        const f32x4* sR = reinterpret_cast<const f32x4*>(ldsR);
        f32x4* dR = reinterpret_cast<f32x4*>(outR + (size_t)e0 * 9);
#pragma unroll
        for (int idx = t; idx < (TPB * 9) / 4; idx += TPB)
            dR[idx] = sR[idx];
        const f32x4* sW = reinterpret_cast<const f32x4*>(ldsW);
        f32x4* dW = reinterpret_cast<f32x4*>(outWm + (size_t)e0 * 81);
        for (int idx = t; idx < (TPB * 81) / 4; idx += TPB)
            dW[idx] = sW[idx];
    } else {
        float* dR = outR + (size_t)e0 * 9;
        for (int idx = t; idx < nvalid * 9; idx += TPB) dR[idx] = ldsR[idx];
        float* dW = outWm + (size_t)e0 * 81;
        for (int idx = t; idx < nvalid * 81; idx += TPB) dW[idx] = ldsW[idx];
    }
    wave_lds_fence();   // wm ds_reads must retire before ldsW is overwritten

    // ---------------- build wm_inv = wm^T (static layout) ----------------
    {
        float* w = &ldsW[t * 81];
        w[0] = 1.f;
#pragma unroll
        for (int c = 1; c < 9; ++c) w[c] = 0.f;
#pragma unroll
        for (int j = 0; j < 3; ++j) {
            float* r = &w[(1 + j) * 9];
            r[0] = 0.f; r[1] = D1[1][j]; r[2] = 0.f; r[3] = D1[2][j];
            r[4] = 0.f; r[5] = D1[0][j]; r[6] = 0.f; r[7] = 0.f; r[8] = 0.f;
        }
#pragma unroll
        for (int c = 0; c < 5; ++c) {
            float* r = &w[(4 + c) * 9];
            r[0] = 0.f; r[1] = 0.f; r[2] = D2[2][c]; r[3] = 0.f;
            r[4] = D2[3][c]; r[5] = 0.f; r[6] = D2[1][c];
            r[7] = D2[4][c]; r[8] = D2[0][c];
        }
    }
    wave_lds_fence();

    // ---------------- copy-out wm_inv ----------------
    if (nvalid == TPB) {
        const f32x4* sW = reinterpret_cast<const f32x4*>(ldsW);
        f32x4* dW = reinterpret_cast<f32x4*>(outWi + (size_t)e0 * 81);
        for (int idx = t; idx < (TPB * 81) / 4; idx += TPB)
            dW[idx] = sW[idx];
    } else {
        float* dW = outWi + (size_t)e0 * 81;
        for (int idx = t; idx < nvalid * 81; idx += TPB) dW[idx] = ldsW[idx];
    }
}

extern "C" void kernel_launch(void* const* d_in, const int* in_sizes, int n_in,
                              void* d_out, int out_size, void* d_ws, size_t ws_size,
                              hipStream_t stream) {
    const float* vec = (const float*)d_in[0];
    const float* rnd = (const float*)d_in[1];
    const float* J1  = (const float*)d_in[2];
    const float* J2  = (const float*)d_in[3];
    float* out = (float*)d_out;

    const int E = in_sizes[0] / 3;
    float* outR  = out;
    float* outWm = out + (size_t)E * 9;
    float* outWi = out + (size_t)E * 90;

    const int blocks = (E + TPB - 1) / TPB;
    hipLaunchKernelGGL(wigner_kernel, dim3(blocks), dim3(TPB), 0, stream,
                       vec, rnd, J1, J2, outR, outWm, outWi, E);
}

// Round 9
// 108.816 us; speedup vs baseline: 1.0579x; 1.0579x over previous
//
#include <hip/hip_runtime.h>
#include <hip/hip_bf16.h>
#include <math.h>

#define TPB 64

typedef float f32x4 __attribute__((ext_vector_type(4)));

// Wave-local LDS fence: workgroup == 1 wave, so cross-lane LDS visibility only
// needs lgkmcnt(0); sched_barrier(0) keeps the compiler from hoisting LDS ops past it.
__device__ __forceinline__ void wave_lds_fence() {
    __builtin_amdgcn_sched_barrier(0);
    asm volatile("s_waitcnt lgkmcnt(0)" ::: "memory");
    __builtin_amdgcn_sched_barrier(0);
}

// D = Za @ J @ Zb @ J @ Zc  (reference z-rot structure: Z[i][i]=cs[i], Z[i][DIM-1-i]=sn[i])
template<int DIM>
__device__ __forceinline__ void zchain(
    const float* __restrict__ J,
    const float (&ca)[DIM], const float (&sa)[DIM],
    const float (&cb)[DIM], const float (&sb)[DIM],
    const float (&cc)[DIM], const float (&sc)[DIM],
    float (&D)[DIM][DIM])
{
    constexpr int d1 = DIM - 1;
    float Jl[DIM][DIM];
#pragma unroll
    for (int i = 0; i < DIM; ++i)
#pragma unroll
        for (int j = 0; j < DIM; ++j)
            Jl[i][j] = J[i * DIM + j];   // uniform -> scalar loads

    float U[DIM][DIM];
#pragma unroll
    for (int i = 0; i < DIM; ++i)
#pragma unroll
        for (int j = 0; j < DIM; ++j)
            U[i][j] = ca[i] * Jl[i][j] + sa[i] * Jl[d1 - i][j];     // Za @ J

    float V[DIM][DIM];
#pragma unroll
    for (int i = 0; i < DIM; ++i)
#pragma unroll
        for (int j = 0; j < DIM; ++j)
            V[i][j] = U[i][j] * cb[j] + U[i][d1 - j] * sb[d1 - j];  // (.) @ Zb

    float W[DIM][DIM];
#pragma unroll
    for (int i = 0; i < DIM; ++i)
#pragma unroll
        for (int j = 0; j < DIM; ++j) {
            float acc = 0.f;
#pragma unroll
            for (int k = 0; k < DIM; ++k)
                acc = fmaf(V[i][k], Jl[k][j], acc);                 // (.) @ J
            W[i][j] = acc;
        }
#pragma unroll
    for (int i = 0; i < DIM; ++i)
#pragma unroll
        for (int j = 0; j < DIM; ++j)
            D[i][j] = W[i][j] * cc[j] + W[i][d1 - j] * sc[d1 - j];  // (.) @ Zc
}

// to_m permutation (reference _build_to_m): order = [0,2,6,3,7,1,5,8,4]
// => wm rows (m=0..8) come from: e0, D1r1, D2r2, D1r2, D2r3, D1r0, D2r1, D2r4, D2r0; wm_inv = wm^T.

__global__ __launch_bounds__(TPB) void wigner_kernel(
    const float* __restrict__ vec, const float* __restrict__ rnd,
    const float* __restrict__ J1,  const float* __restrict__ J2,
    float* __restrict__ outR,
    float* __restrict__ outWm,
    float* __restrict__ outWi,
    int E)
{
    __shared__ __align__(16) float ldsR[TPB * 9];
    __shared__ __align__(16) float ldsW[TPB * 81];

    const int t  = threadIdx.x;
    const int e0 = blockIdx.x * TPB;
    const int e  = e0 + t;
    const int ei = (e < E) ? e : (E - 1);
    const int nvalid = min(TPB, E - e0);

    // ---------------- per-edge math (f32, no transcendentals) ----------------
    float vx = vec[3 * ei + 0], vy = vec[3 * ei + 1], vz = vec[3 * ei + 2];
    float rn = rsqrtf(vx * vx + vy * vy + vz * vz);
    float nx0 = vx * rn, nx1 = vy * rn, nx2 = vz * rn;     // norm_x

    float ox = rnd[3 * ei + 0] - 0.5f;
    float oy = rnd[3 * ei + 1] - 0.5f;
    float oz = rnd[3 * ei + 2] - 0.5f;
    float ro = rsqrtf(ox * ox + oy * oy + oz * oz);
    ox *= ro; oy *= ro; oz *= ro;                          // original e2

    // candidate selection (e2b, e2c from ORIGINAL e2)
    float sx = ox, sy = oy, sz = oz;
    float dcur = fabsf(sx * nx0 + sy * nx1 + sz * nx2);
    {
        float bx = -oy, by = ox, bz = oz;
        float db = fabsf(bx * nx0 + by * nx1 + bz * nx2);
        if (dcur > db) { sx = bx; sy = by; sz = bz; dcur = db; }
        float cx = ox, cy = -oz, cz = oy;
        float dc = fabsf(cx * nx0 + cy * nx1 + cz * nx2);
        if (dcur > dc) { sx = cx; sy = cy; sz = cz; }
    }

    // norm_z = normalize(cross(norm_x, e2))
    float zx = nx1 * sz - nx2 * sy;
    float zy = nx2 * sx - nx0 * sz;
    float zz = nx0 * sy - nx1 * sx;
    float rz = rsqrtf(zx * zx + zy * zy + zz * zz);
    zx *= rz; zy *= rz; zz *= rz;

    // norm_y = normalize(cross(norm_x, norm_z))
    float yx = nx1 * zz - nx2 * zy;
    float yy = nx2 * zx - nx0 * zz;
    float yz = nx0 * zy - nx1 * zx;
    float ry = rsqrtf(yx * yx + yy * yy + yz * yz);
    yx *= ry; yy *= ry; yz *= ry;

    // ---- sin/cos of Euler angles, algebraically (no atan2/acos/sincos) ----
    float h2a = zy * zy + yy * yy;
    float rha = rsqrtf(fmaxf(h2a, 1e-30f));
    bool  za  = (h2a < 1e-24f);
    float sa  = za ? 0.f : zy * rha;
    float caa = za ? 1.f : yy * rha;
    float cbb = fminf(1.f, fmaxf(-1.f, nx1));
    float sb  = sqrtf(fmaxf(0.f, 1.f - cbb * cbb));
    float gy  = caa * zz - sa * yz;
    float gx  = caa * zx - sa * yx;
    float h2g = gy * gy + gx * gx;
    float rhg = rsqrtf(fmaxf(h2g, 1e-30f));
    bool  zg  = (h2g < 1e-24f);
    float sg  = zg ? 0.f : gy * rhg;
    float cgg = zg ? 1.f : gx * rhg;

    // l = 1 block
    float ca3[3] = {caa, 1.f, caa}, sa3[3] = {sa, 0.f, -sa};
    float cb3[3] = {cbb, 1.f, cbb}, sb3[3] = {sb, 0.f, -sb};
    float cc3[3] = {cgg, 1.f, cgg}, sc3[3] = {sg, 0.f, -sg};
    float D1[3][3];
    zchain<3>(J1, ca3, sa3, cb3, sb3, cc3, sc3, D1);

    // l = 2 block (double angles via identities)
    float ca2 = caa * caa - sa * sa,  sa2 = 2.f * sa * caa;
    float cb2 = cbb * cbb - sb * sb,  sb2 = 2.f * sb * cbb;
    float cg2 = cgg * cgg - sg * sg,  sg2 = 2.f * sg * cgg;
    float ca5[5] = {ca2, caa, 1.f, caa, ca2}, sa5[5] = {sa2, sa, 0.f, -sa, -sa2};
    float cb5[5] = {cb2, cbb, 1.f, cbb, cb2}, sb5[5] = {sb2, sb, 0.f, -sb, -sb2};
    float cc5[5] = {cg2, cgg, 1.f, cgg, cg2}, sc5[5] = {sg2, sg, 0.f, -sg, -sg2};
    float D2[5][5];
    zchain<5>(J2, ca5, sa5, cb5, sb5, cc5, sc5, D2);

    // ---------------- build R and wm (static layout) ----------------
    {
        float* r9 = &ldsR[t * 9];
        r9[0] = zx;  r9[1] = zy;  r9[2] = zz;
        r9[3] = nx0; r9[4] = nx1; r9[5] = nx2;
        r9[6] = yx;  r9[7] = yy;  r9[8] = yz;

        float* w = &ldsW[t * 81];
        w[0] = 1.f;
#pragma unroll
        for (int c = 1; c < 9; ++c) w[c] = 0.f;
        w[9]  = 0.f; w[10] = D1[1][0]; w[11] = D1[1][1]; w[12] = D1[1][2];
#pragma unroll
        for (int c = 4; c < 9; ++c) w[9 + c] = 0.f;
#pragma unroll
        for (int c = 0; c < 4; ++c) w[18 + c] = 0.f;
#pragma unroll
        for (int c = 0; c < 5; ++c) w[22 + c] = D2[2][c];
        w[27] = 0.f; w[28] = D1[2][0]; w[29] = D1[2][1]; w[30] = D1[2][2];
#pragma unroll
        for (int c = 4; c < 9; ++c) w[27 + c] = 0.f;
#pragma unroll
        for (int c = 0; c < 4; ++c) w[36 + c] = 0.f;
#pragma unroll
        for (int c = 0; c < 5; ++c) w[40 + c] = D2[3][c];
        w[45] = 0.f; w[46] = D1[0][0]; w[47] = D1[0][1]; w[48] = D1[0][2];
#pragma unroll
        for (int c = 4; c < 9; ++c) w[45 + c] = 0.f;
#pragma unroll
        for (int c = 0; c < 4; ++c) w[54 + c] = 0.f;
#pragma unroll
        for (int c = 0; c < 5; ++c) w[58 + c] = D2[1][c];
#pragma unroll
        for (int c = 0; c < 4; ++c) w[63 + c] = 0.f;
#pragma unroll
        for (int c = 0; c < 5; ++c) w[67 + c] = D2[4][c];
#pragma unroll
        for (int c = 0; c < 4; ++c) w[72 + c] = 0.f;
#pragma unroll
        for (int c = 0; c < 5; ++c) w[76 + c] = D2[0][c];
    }
    wave_lds_fence();

    // ------- copy-out R and wm: BATCHED unrolled ds_reads, then NT stores -------
    if (nvalid == TPB) {
        // R: 144 f32x4 chunks; k=0,1 full, k=2 only lanes t<16
        {
            const f32x4* sR = reinterpret_cast<const f32x4*>(ldsR);
            f32x4* dR = reinterpret_cast<f32x4*>(outR + (size_t)e0 * 9);
            f32x4 bR[3];
#pragma unroll
            for (int k = 0; k < 2; ++k) bR[k] = sR[t + 64 * k];
            if (t < 16) bR[2] = sR[t + 128];
#pragma unroll
            for (int k = 0; k < 2; ++k)
                __builtin_nontemporal_store(bR[k], &dR[t + 64 * k]);
            if (t < 16) __builtin_nontemporal_store(bR[2], &dR[t + 128]);
        }
        // wm: 1296 f32x4 chunks; k=0..19 full, k=20 only lanes t<16
        {
            const f32x4* sW = reinterpret_cast<const f32x4*>(ldsW);
            f32x4* dW = reinterpret_cast<f32x4*>(outWm + (size_t)e0 * 81);
            f32x4 bW[21];
#pragma unroll
            for (int k = 0; k < 20; ++k) bW[k] = sW[t + 64 * k];
            if (t < 16) bW[20] = sW[t + 1280];
#pragma unroll
            for (int k = 0; k < 20; ++k)
                __builtin_nontemporal_store(bW[k], &dW[t + 64 * k]);
            if (t < 16) __builtin_nontemporal_store(bW[20], &dW[t + 1280]);
        }
    } else {
        float* dR = outR + (size_t)e0 * 9;
        for (int idx = t; idx < nvalid * 9; idx += TPB) dR[idx] = ldsR[idx];
        float* dW = outWm + (size_t)e0 * 81;
        for (int idx = t; idx < nvalid * 81; idx += TPB) dW[idx] = ldsW[idx];
    }
    wave_lds_fence();   // wm ds_reads retired before ldsW is overwritten

    // ---------------- build wm_inv = wm^T (static layout) ----------------
    {
        float* w = &ldsW[t * 81];
        w[0] = 1.f;
#pragma unroll
        for (int c = 1; c < 9; ++c) w[c] = 0.f;
#pragma unroll
        for (int j = 0; j < 3; ++j) {
            float* r = &w[(1 + j) * 9];
            r[0] = 0.f; r[1] = D1[1][j]; r[2] = 0.f; r[3] = D1[2][j];
            r[4] = 0.f; r[5] = D1[0][j]; r[6] = 0.f; r[7] = 0.f; r[8] = 0.f;
        }
#pragma unroll
        for (int c = 0; c < 5; ++c) {
            float* r = &w[(4 + c) * 9];
            r[0] = 0.f; r[1] = 0.f; r[2] = D2[2][c]; r[3] = 0.f;
            r[4] = D2[3][c]; r[5] = 0.f; r[6] = D2[1][c];
            r[7] = D2[4][c]; r[8] = D2[0][c];
        }
    }
    wave_lds_fence();

    // ---------------- copy-out wm_inv: batched unrolled ----------------
    if (nvalid == TPB) {
        const f32x4* sW = reinterpret_cast<const f32x4*>(ldsW);
        f32x4* dW = reinterpret_cast<f32x4*>(outWi + (size_t)e0 * 81);
        f32x4 bW[21];
#pragma unroll
        for (int k = 0; k < 20; ++k) bW[k] = sW[t + 64 * k];
        if (t < 16) bW[20] = sW[t + 1280];
#pragma unroll
        for (int k = 0; k < 20; ++k)
            __builtin_nontemporal_store(bW[k], &dW[t + 64 * k]);
        if (t < 16) __builtin_nontemporal_store(bW[20], &dW[t + 1280]);
    } else {
        float* dW = outWi + (size_t)e0 * 81;
        for (int idx = t; idx < nvalid * 81; idx += TPB) dW[idx] = ldsW[idx];
    }
}

extern "C" void kernel_launch(void* const* d_in, const int* in_sizes, int n_in,
                              void* d_out, int out_size, void* d_ws, size_t ws_size,
                              hipStream_t stream) {
    const float* vec = (const float*)d_in[0];
    const float* rnd = (const float*)d_in[1];
    const float* J1  = (const float*)d_in[2];
    const float* J2  = (const float*)d_in[3];
    float* out = (float*)d_out;

    const int E = in_sizes[0] / 3;
    float* outR  = out;
    float* outWm = out + (size_t)E * 9;
    float* outWi = out + (size_t)E * 90;

    const int blocks = (E + TPB - 1) / TPB;
    hipLaunchKernelGGL(wigner_kernel, dim3(blocks), dim3(TPB), 0, stream,
                       vec, rnd, J1, J2, outR, outWm, outWi, E);
}